// Round 4
// baseline (1138.632 us; speedup 1.0000x reference)
//
#include <hip/hip_runtime.h>
#include <stdint.h>

namespace {

constexpr int BROWS = 1024;   // batch
constexpr int NIT   = 50000;  // n_items
constexpr int NH1   = 600;
constexpr int NH2   = 200;
constexpr int KXP   = 50048;  // NIT padded to x64 (K of gemm1)
constexpr int N1P   = 640;    // NH1 padded to x128 (N of gemm1)
constexpr int NEP   = 50048;  // NIT padded to x128 (N of dist gemm)
constexpr int KEP   = 640;    // NH1 padded to x64  (K of dist gemm)
constexpr int KI64_TOTAL = KXP / 64;  // 782 k-steps of 64
constexpr int NBLK1 = N1P / 128;      // 5  (gemm1 n-blocks)
constexpr int NBLK4 = NEP / 128;      // 391 (dist n-blocks)
constexpr int TGRID = (KXP / 64) * (N1P / 64);  // 7820 transpose tiles

typedef _Float16 f16x8 __attribute__((ext_vector_type(8)));
typedef _Float16 f16x4 __attribute__((ext_vector_type(4)));
typedef _Float16 f16x2 __attribute__((ext_vector_type(2)));
typedef float    f32x4 __attribute__((ext_vector_type(4)));

__device__ __forceinline__ void gld16(const void* g, void* l) {
  // async global->LDS, 16B per lane; LDS dest must be uniform-base + lane*16
  __builtin_amdgcn_global_load_lds(
      (__attribute__((address_space(1))) void*)(void*)g,
      (__attribute__((address_space(3))) void*)l, 16, 0, 0);
}

// ---------------- fused prep: blocks [0,1024) = x row-norm + f16 convert;
//                  blocks [1024, 1024+TGRID) = W1 [K,N] -> W1T f16 [N1P][KXP]
__global__ __launch_bounds__(256) void prep_fused_k(const float* __restrict__ x,
                                                    float* __restrict__ invnorm,
                                                    _Float16* __restrict__ xh,
                                                    const float* __restrict__ W1,
                                                    _Float16* __restrict__ W1T) {
  __shared__ float tile[64][65];
  __shared__ float red[4];
  const int t = threadIdx.x;
  if (blockIdx.x < BROWS) {
    const int row = blockIdx.x;
    const float4* xr = (const float4*)(x + (size_t)row * NIT);
    float ss = 0.f;
    if (xh != nullptr) {
      f16x4* xo = (f16x4*)(xh + (size_t)row * KXP);
      #pragma unroll 4
      for (int i = t; i < NIT / 4; i += 256) {
        float4 v = xr[i];
        ss += v.x * v.x + v.y * v.y + v.z * v.z + v.w * v.w;
        f16x4 h;
        h.x = (_Float16)v.x; h.y = (_Float16)v.y;
        h.z = (_Float16)v.z; h.w = (_Float16)v.w;
        xo[i] = h;
      }
      if (t < (KXP - NIT) / 4) {  // pad k=50000..50047
        f16x4 z;
        z.x = (_Float16)0.f; z.y = (_Float16)0.f;
        z.z = (_Float16)0.f; z.w = (_Float16)0.f;
        xo[NIT / 4 + t] = z;
      }
    } else {
      #pragma unroll 4
      for (int i = t; i < NIT / 4; i += 256) {
        float4 v = xr[i];
        ss += v.x * v.x + v.y * v.y + v.z * v.z + v.w * v.w;
      }
    }
    for (int o = 32; o > 0; o >>= 1) ss += __shfl_down(ss, o);
    if ((t & 63) == 0) red[t >> 6] = ss;
    __syncthreads();
    if (t == 0) {
      float s = red[0] + red[1] + red[2] + red[3];
      invnorm[row] = 1.0f / fmaxf(sqrtf(s), 1e-12f);
    }
  } else {
    const int tb = blockIdx.x - BROWS;
    const int kb = (tb % (KXP / 64)) * 64;
    const int nb = (tb / (KXP / 64)) * 64;
    #pragma unroll
    for (int i = 0; i < 16; ++i) {
      int idx = i * 256 + t;
      int k = idx >> 6, n = idx & 63;
      int gk = kb + k, gn = nb + n;
      tile[k][n] = (gk < NIT && gn < NH1) ? W1[(size_t)gk * NH1 + gn] : 0.f;
    }
    __syncthreads();
    #pragma unroll
    for (int i = 0; i < 8; ++i) {
      int idx = i * 256 + t;        // 0..2047
      int n = idx >> 5;             // 0..63
      int k2 = (idx & 31) * 2;      // 0..62 (even)
      f16x2 h;
      h.x = (_Float16)tile[k2][n];
      h.y = (_Float16)tile[k2 + 1][n];
      *(f16x2*)(&W1T[(size_t)(nb + n) * KXP + kb + k2]) = h;
    }
  }
}

// -------------------------------------------------- gemm1: MFMA NT 128x128x64
// (unchanged from verified round-3 version)
// MODE 0: C1-partial = x(fp32, reg-staged+cvt) @ W1T^T, split-K (gridDim.z)
// MODE 2: C1-partial = xh(f16, gld16-staged)  @ W1T^T, split-K (gridDim.z)
template <int MODE>
__global__ __launch_bounds__(256, 4) void mfma_nt_k(
    const void* __restrict__ Av, const _Float16* __restrict__ Bg,
    float* __restrict__ Cout) {
  __shared__ _Float16 As[128 * 64];
  __shared__ _Float16 Bs[128 * 64];

  const int t = threadIdx.x;

  const int S = (int)gridDim.z;
  int flat = blockIdx.x + NBLK1 * (blockIdx.y + 8 * blockIdx.z);  // nwg = 40*S, %8==0
  int W = (flat & 7) * (5 * S) + (flat >> 3);
  int xq = W % 5;
  int yz = W / 5;
  const int n0 = xq * 128;   // x fastest: 5 consecutive blocks share A m-slice
  const int m0 = (yz & 7) * 128;
  const int zslab = yz >> 3;
  int kiPer = (KI64_TOTAL + S - 1) / S;
  int ki0 = zslab * kiPer;
  int ki1 = ki0 + kiPer; if (ki1 > KI64_TOTAL) ki1 = KI64_TOTAL;
  const int lda = (MODE == 0) ? NIT : KXP;
  const int ldb = KXP;

  const int lane = t & 63;
  const int wid = t >> 6;
  const int wm = wid >> 1, wn = wid & 1;
  const int lrow = lane & 15, quad = lane >> 4;

  const f32x4 zero = {0.f, 0.f, 0.f, 0.f};
  f32x4 acc[4][4];
  #pragma unroll
  for (int i = 0; i < 4; ++i)
    #pragma unroll
    for (int j = 0; j < 4; ++j) acc[i][j] = zero;

  for (int ki = ki0; ki < ki1; ++ki) {
    const int k0 = ki * 64;
    if (MODE == 0) {
      const float* A = (const float*)Av;
      #pragma unroll
      for (int j = 0; j < 8; ++j) {
        int g = j * 256 + t;          // 0..2047 float4 units
        int row = g >> 4;             // 0..127
        int q4 = g & 15;              // float4 within row
        int kcol = k0 + q4 * 4;
        float4 v = {0.f, 0.f, 0.f, 0.f};
        if (kcol < NIT)
          v = *(const float4*)(A + (size_t)(m0 + row) * lda + kcol);
        f16x4 h;
        h.x = (_Float16)v.x; h.y = (_Float16)v.y;
        h.z = (_Float16)v.z; h.w = (_Float16)v.w;
        int c16 = (q4 >> 1) ^ (row & 7);   // swizzled 16B-chunk col
        *(f16x4*)(&As[row * 64 + c16 * 8 + (q4 & 1) * 4]) = h;
      }
    } else {
      const _Float16* A = (const _Float16*)Av;
      #pragma unroll
      for (int j = 0; j < 4; ++j) {
        int c = j * 256 + t;          // 16B-chunk id, 0..1023
        int row = c >> 3;             // 0..127
        int kk = ((c & 7) ^ (row & 7)) << 3;  // XOR-permuted SOURCE k (f16)
        gld16(A + (size_t)(m0 + row) * lda + (k0 + kk), &As[c * 8]);
      }
    }
    #pragma unroll
    for (int j = 0; j < 4; ++j) {
      int c = j * 256 + t;
      int row = c >> 3;
      int kk = ((c & 7) ^ (row & 7)) << 3;
      gld16(Bg + (size_t)(n0 + row) * ldb + (k0 + kk), &Bs[c * 8]);
    }
    __syncthreads();

    #pragma unroll
    for (int ks = 0; ks < 2; ++ks) {
      f16x8 af[4], bfr[4];
      #pragma unroll
      for (int mi = 0; mi < 4; ++mi) {
        int row = wm * 64 + mi * 16 + lrow;
        int c16 = (ks * 4 + quad) ^ (lrow & 7);
        af[mi] = *(const f16x8*)(&As[row * 64 + c16 * 8]);
      }
      #pragma unroll
      for (int ni = 0; ni < 4; ++ni) {
        int row = wn * 64 + ni * 16 + lrow;
        int c16 = (ks * 4 + quad) ^ (lrow & 7);
        bfr[ni] = *(const f16x8*)(&Bs[row * 64 + c16 * 8]);
      }
      #pragma unroll
      for (int mi = 0; mi < 4; ++mi)
        #pragma unroll
        for (int ni = 0; ni < 4; ++ni)
          acc[mi][ni] = __builtin_amdgcn_mfma_f32_16x16x32_f16(af[mi], bfr[ni],
                                                               acc[mi][ni], 0, 0, 0);
    }
    __syncthreads();
  }

  float* Cs = Cout + (size_t)zslab * BROWS * N1P;
  #pragma unroll
  for (int mi = 0; mi < 4; ++mi)
    #pragma unroll
    for (int r = 0; r < 4; ++r) {
      int row = m0 + wm * 64 + mi * 16 + quad * 4 + r;
      #pragma unroll
      for (int ni = 0; ni < 4; ++ni) {
        int col = n0 + wn * 64 + ni * 16 + lrow;
        Cs[(size_t)row * N1P + col] = acc[mi][ni][r];
      }
    }
}

// ---------------------------------------------- dist GEMM, 128x128x64, dbuf
// A = h3h f16 (gld16, swizzled source); B = emb f32 reg-staged+cvt (T14:
// loads issued before MFMA, ds_write after); esq computed inline (f32 exact);
// epilogue through LDS -> coalesced nontemporal dwordx4 stores.
__global__ __launch_bounds__(256, 2) void dist_k(
    const _Float16* __restrict__ h3h, const float* __restrict__ emb,
    float* __restrict__ out, const float* __restrict__ hsq) {
  __shared__ __align__(16) _Float16 smem[4][128 * 64];  // As[2] | Bs[2]; 64 KB
  __shared__ float esqs[128];

  const int t = threadIdx.x;
  // T1 bijective remap: grid (391, 8), m fastest within XCD chunk
  int flat = blockIdx.x + NBLK4 * blockIdx.y;     // 3128 % 8 == 0
  int W = (flat & 7) * NBLK4 + (flat >> 3);
  const int m0 = (W & 7) * 128;
  const int n0 = (W >> 3) * 128;
  constexpr int KI1 = KEP / 64;   // 10

  const int lane = t & 63;
  const int wid = t >> 6;
  const int wm = wid >> 1, wn = wid & 1;
  const int lrow = lane & 15, quad = lane >> 4;

  const f32x4 zero = {0.f, 0.f, 0.f, 0.f};
  f32x4 acc[4][4];
  #pragma unroll
  for (int i = 0; i < 4; ++i)
    #pragma unroll
    for (int j = 0; j < 4; ++j) acc[i][j] = zero;

  float ssq[8];
  #pragma unroll
  for (int j = 0; j < 8; ++j) ssq[j] = 0.f;

  const int rA = t >> 3;                 // gld16 A helper indices
  const int kkA = ((t & 7) ^ (rA & 7)) << 3;
  const int rB = t >> 4;                 // B reg-stage: row base (per j: j*16+rB)
  const int q4 = t & 15;

  auto stageA = [&](int buf, int ki) {
    const int k0 = ki * 64;
    #pragma unroll
    for (int j = 0; j < 4; ++j) {
      int c = j * 256 + t;
      int row = c >> 3;
      int kk = ((c & 7) ^ (row & 7)) << 3;
      gld16(h3h + (size_t)(m0 + row) * KEP + (k0 + kk), &smem[buf][c * 8]);
    }
  };
  auto loadB = [&](int ki, float4* v) {
    const int k0 = ki * 64;
    const int kcol = k0 + q4 * 4;
    #pragma unroll
    for (int j = 0; j < 8; ++j) {
      int row = j * 16 + rB;
      float4 vv = {0.f, 0.f, 0.f, 0.f};
      if (kcol < NH1 && (n0 + row) < NIT)
        vv = *(const float4*)(emb + (size_t)(n0 + row) * NH1 + kcol);
      v[j] = vv;
    }
  };
  auto writeB = [&](int buf, const float4* v) {
    #pragma unroll
    for (int j = 0; j < 8; ++j) {
      float4 vv = v[j];
      ssq[j] += vv.x * vv.x + vv.y * vv.y + vv.z * vv.z + vv.w * vv.w;
      f16x4 h;
      h.x = (_Float16)vv.x; h.y = (_Float16)vv.y;
      h.z = (_Float16)vv.z; h.w = (_Float16)vv.w;
      int row = j * 16 + rB;
      int c16 = (q4 >> 1) ^ (row & 7);
      *(f16x4*)(&smem[2 + buf][row * 64 + c16 * 8 + (q4 & 1) * 4]) = h;
    }
  };

  // prologue
  {
    float4 v[8];
    loadB(0, v);
    stageA(0, 0);
    writeB(0, v);
  }
  __syncthreads();

  int cur = 0;
  for (int ki = 0; ki < KI1; ++ki) {
    float4 v[8];
    const bool more = (ki + 1 < KI1);
    if (more) {
      stageA(cur ^ 1, ki + 1);   // async -> LDS
      loadB(ki + 1, v);          // issue global loads (consumed after MFMA)
    }
    #pragma unroll
    for (int ks = 0; ks < 2; ++ks) {
      f16x8 af[4], bfr[4];
      #pragma unroll
      for (int mi = 0; mi < 4; ++mi) {
        int row = wm * 64 + mi * 16 + lrow;
        int c16 = (ks * 4 + quad) ^ (lrow & 7);
        af[mi] = *(const f16x8*)(&smem[cur][row * 64 + c16 * 8]);
      }
      #pragma unroll
      for (int ni = 0; ni < 4; ++ni) {
        int row = wn * 64 + ni * 16 + lrow;
        int c16 = (ks * 4 + quad) ^ (lrow & 7);
        bfr[ni] = *(const f16x8*)(&smem[2 + cur][row * 64 + c16 * 8]);
      }
      #pragma unroll
      for (int mi = 0; mi < 4; ++mi)
        #pragma unroll
        for (int ni = 0; ni < 4; ++ni)
          acc[mi][ni] = __builtin_amdgcn_mfma_f32_16x16x32_f16(af[mi], bfr[ni],
                                                               acc[mi][ni], 0, 0, 0);
    }
    if (more) writeB(cur ^ 1, v);  // vmcnt wait lands here, hidden under MFMA
    __syncthreads();
    cur ^= 1;
  }

  // esq: reduce each row-partial over its 16-thread group (exact f32)
  #pragma unroll
  for (int j = 0; j < 8; ++j) {
    float s = ssq[j];
    s += __shfl_down(s, 8, 16);
    s += __shfl_down(s, 4, 16);
    s += __shfl_down(s, 2, 16);
    s += __shfl_down(s, 1, 16);
    if (q4 == 0) esqs[j * 16 + rB] = s;
  }
  __syncthreads();

  // epilogue: finalize in regs -> LDS f32 tile -> coalesced nt stores
  float* ctile = (float*)smem;  // 128*128 f32 = 64 KB
  #pragma unroll
  for (int mi = 0; mi < 4; ++mi)
    #pragma unroll
    for (int r = 0; r < 4; ++r) {
      int rl = wm * 64 + mi * 16 + quad * 4 + r;
      float hv = hsq[m0 + rl];
      #pragma unroll
      for (int ni = 0; ni < 4; ++ni) {
        int cl = wn * 64 + ni * 16 + lrow;
        ctile[rl * 128 + cl] = hv - 2.f * acc[mi][ni][r] + esqs[cl];
      }
    }
  __syncthreads();
  #pragma unroll
  for (int i = 0; i < 16; ++i) {
    int c4 = i * 256 + t;          // f32x4 id, 0..4095
    int row = c4 >> 5;             // 0..127
    int cq = c4 & 31;
    int col = n0 + cq * 4;
    if (col < NIT) {               // NIT%4==0 -> all-or-nothing
      f32x4 v = *(const f32x4*)(&ctile[row * 128 + cq * 4]);
      __builtin_nontemporal_store(v, (f32x4*)(out + (size_t)(m0 + row) * NIT + col));
    }
  }
}

// --------------- fused: h1 = tanh(invn*sum_slabs(C1p)+b1); h2 = tanh(h1@W2+b2)
__global__ __launch_bounds__(256) void gemm2f_k(const float* __restrict__ C1p,
                                                const float* __restrict__ invnorm,
                                                const float* __restrict__ b1,
                                                const float* __restrict__ W2,
                                                const float* __restrict__ b2,
                                                float* __restrict__ h2,
                                                int nslabs) {
  __shared__ float hs[8 * NH1];
  const int m0 = blockIdx.x * 8;
  const int t = threadIdx.x;
  for (int i = t; i < 8 * NH1; i += 256) {
    int m = i / NH1, n = i - m * NH1;
    float s = 0.f;
    for (int sp = 0; sp < nslabs; ++sp)
      s += C1p[(size_t)sp * BROWS * N1P + (size_t)(m0 + m) * N1P + n];
    hs[i] = tanhf(invnorm[m0 + m] * s + b1[n]);
  }
  __syncthreads();
  if (t < NH2) {
    float acc[8];
    #pragma unroll
    for (int r = 0; r < 8; ++r) acc[r] = 0.f;
    for (int k0 = 0; k0 < NH1; k0 += 8) {   // 600 = 75 * 8
      float w[8];
      #pragma unroll
      for (int u = 0; u < 8; ++u) w[u] = W2[(k0 + u) * NH2 + t];
      #pragma unroll
      for (int u = 0; u < 8; ++u)
        #pragma unroll
        for (int r = 0; r < 8; ++r) acc[r] += hs[r * NH1 + k0 + u] * w[u];
    }
    float bb = b2[t];
    #pragma unroll
    for (int r = 0; r < 8; ++r) h2[(size_t)(m0 + r) * NH2 + t] = tanhf(acc[r] + bb);
  }
}

// --------------------- h3 = tanh(h2 @ W3 + b3) -> f16 [BROWS][KEP] + hsq
__global__ __launch_bounds__(256) void gemm3_k(const float* __restrict__ h2,
                                               const float* __restrict__ W3,
                                               const float* __restrict__ b3,
                                               _Float16* __restrict__ h3h,
                                               float* __restrict__ hsq) {
  __shared__ float hs[8 * NH2];
  const int m0 = blockIdx.x * 8;
  const int t = threadIdx.x;
  for (int i = t; i < 8 * NH2; i += 256) hs[i] = h2[(size_t)m0 * NH2 + i];
  __syncthreads();
  float ssq[8];
  #pragma unroll
  for (int r = 0; r < 8; ++r) ssq[r] = 0.f;
  for (int c = 0; c < 3; ++c) {
    int n = t + c * 256;
    if (n < NH1) {
      float acc[8];
      #pragma unroll
      for (int r = 0; r < 8; ++r) acc[r] = 0.f;
      for (int k0 = 0; k0 < NH2; k0 += 8) {  // 200 = 25 * 8
        float w[8];
        #pragma unroll
        for (int u = 0; u < 8; ++u) w[u] = W3[(k0 + u) * NH1 + n];
        #pragma unroll
        for (int u = 0; u < 8; ++u)
          #pragma unroll
          for (int r = 0; r < 8; ++r) acc[r] += hs[r * NH2 + k0 + u] * w[u];
      }
      float bb = b3[n];
      #pragma unroll
      for (int r = 0; r < 8; ++r) {
        float v = tanhf(acc[r] + bb);
        h3h[(size_t)(m0 + r) * KEP + n] = (_Float16)v;
        ssq[r] += v * v;
      }
    } else if (n < KEP) {
      #pragma unroll
      for (int r = 0; r < 8; ++r) h3h[(size_t)(m0 + r) * KEP + n] = (_Float16)0.f;
    }
  }
  const int lane = t & 63, wid = t >> 6;
  #pragma unroll
  for (int r = 0; r < 8; ++r)
    for (int o = 32; o > 0; o >>= 1) ssq[r] += __shfl_down(ssq[r], o);
  __shared__ float red2[8][4];
  if (lane == 0) {
    #pragma unroll
    for (int r = 0; r < 8; ++r) red2[r][wid] = ssq[r];
  }
  __syncthreads();
  if (t < 8) hsq[m0 + t] = red2[t][0] + red2[t][1] + red2[t][2] + red2[t][3];
}

}  // namespace

extern "C" void kernel_launch(void* const* d_in, const int* in_sizes, int n_in,
                              void* d_out, int out_size, void* d_ws, size_t ws_size,
                              hipStream_t stream) {
  const float* x   = (const float*)d_in[0];
  const float* W1  = (const float*)d_in[1];
  const float* b1  = (const float*)d_in[2];
  const float* W2  = (const float*)d_in[3];
  const float* b2  = (const float*)d_in[4];
  const float* W3  = (const float*)d_in[5];
  const float* b3  = (const float*)d_in[6];
  const float* emb = (const float*)d_in[7];
  float* out = (float*)d_out;

  char* ws = (char*)d_ws;

  const size_t XHSZ  = (size_t)BROWS * KXP * 2;   // 102,498,304 (f16 x, k-padded)
  const size_t W1TSZ = (size_t)N1P * KXP * 2;     //  64,061,440
  const size_t SLAB  = (size_t)BROWS * N1P * 4;   //   2,621,440 per split slab
  const size_t TAIL  = 4096 + 819200 + 1310720 + 4096;  // invn,h2,h3h,hsq

  bool useF16A;
  int S;
  const size_t baseA = XHSZ + W1TSZ + TAIL;
  const size_t baseB = W1TSZ + TAIL;
  if (ws_size >= baseA + 16 * SLAB) {
    useF16A = true;
    size_t s = (ws_size - baseA) / SLAB;
    S = s > 32 ? 32 : (int)s;
  } else if (ws_size >= baseB + 8 * SLAB) {
    useF16A = false;
    size_t s = (ws_size - baseB) / SLAB;
    S = s > 32 ? 32 : (int)s;
  } else {
    return;  // ws too small -> fail visibly (poison output)
  }

  size_t off = 0;
  _Float16* xh = nullptr;
  if (useF16A) { xh = (_Float16*)(ws + off); off += XHSZ; }
  _Float16* W1T = (_Float16*)(ws + off); off += W1TSZ;
  float* C1p = (float*)(ws + off); off += (size_t)S * SLAB;
  float* invn = (float*)(ws + off); off += 4096;
  float* h2   = (float*)(ws + off); off += 819200;
  _Float16* h3h = (_Float16*)(ws + off); off += 1310720;
  float* hsq  = (float*)(ws + off); off += 4096;

  prep_fused_k<<<dim3(BROWS + TGRID), dim3(256), 0, stream>>>(x, invn, xh, W1, W1T);
  if (useF16A) {
    mfma_nt_k<2><<<dim3(NBLK1, BROWS / 128, S), dim3(256), 0, stream>>>(
        (const void*)xh, W1T, C1p);
  } else {
    mfma_nt_k<0><<<dim3(NBLK1, BROWS / 128, S), dim3(256), 0, stream>>>(
        (const void*)x, W1T, C1p);
  }
  gemm2f_k<<<dim3(BROWS / 8), dim3(256), 0, stream>>>(C1p, invn, b1, W2, b2, h2, S);
  gemm3_k<<<dim3(BROWS / 8), dim3(256), 0, stream>>>(h2, W3, b3, h3h, hsq);
  dist_k<<<dim3(NBLK4, BROWS / 128), dim3(256), 0, stream>>>(h3h, emb, out, hsq);
}